// Round 2
// baseline (283.881 us; speedup 1.0000x reference)
//
#include <hip/hip_runtime.h>

// SuperLoss: l = BCE(p,t); y = 0.5*max(-2/e,(l-tau)/lam); w = LambertW(y);
// loss = (l-tau)*sigma + lam*w^2 ; out = sum(loss)/32
//
// Round-2 algebraic restructure (R1: 110us/dispatch, VALUBusy 75%, absmax 0.0):
//  - sigma = exp(-W(y)) == W(y)/y  (identity from W e^W = y). For unclamped
//    elements (l-tau) = 1.8*y, so loss = 1.8w + 0.9w^2 = 0.9*w*(w+2): final
//    exp eliminated. Clamped elements (y=-1/e -> w=-1, sigma=e) use the closed
//    form lt*e + 0.9 via select; their Halley result is discarded.
//  - Halley in single-rcp form: w -= 2f(w+1) / (2e^w(w+1)^2 - (w+2)f + eps)
//  - 2 iterations (vs ref's 12): y<0 init upgraded to 3-term branch series
//    (worst init err ~0.25; cubic convergence -> <=4e-8 after two iters).
//    Error budget: threshold 1.9e4 on the ~9.5e5 sum; even fully-correlated
//    per-element error of 1e-4 sums to ~6e3. Huge margin.
// Transcendental count: 17 -> 8 per element (2 log BCE + sqrt + log init +
// 2x(exp+rcp)).

#define TAU_F       1.5f
#define LAM_F       0.9f
#define E_F         2.718281828459045f
#define NEG_INV_E_F -0.36787944117144233f
#define INV_2LAM_F  0.5555555555555556f    // 1/(2*0.9) = 1/1.8
#define LOG2E_F     1.4426950408889634f
#define LN2_F       0.6931471805599453f

__device__ __forceinline__ float fexp2(float x) { return __builtin_amdgcn_exp2f(x); }
__device__ __forceinline__ float flog2(float x) { return __builtin_amdgcn_logf(x); }
__device__ __forceinline__ float frcp(float x)  { return __builtin_amdgcn_rcpf(x); }
__device__ __forceinline__ float fsqrt(float x) { return __builtin_amdgcn_sqrtf(x); }

__device__ __forceinline__ float superloss_elem(float p, float t) {
    // BCE: l = -(t*ln p + (1-t)*ln(1-p)) = -LN2*(lg1p + t*(lgp - lg1p))
    // (-100 clamp inactive: p in [1e-6, 1-1e-6] -> ln p >= -13.9)
    float lgp  = flog2(p);
    float lg1p = flog2(1.0f - p);
    float l    = -LN2_F * fmaf(t, lgp - lg1p, lg1p);
    float lt   = l - TAU_F;
    float y    = lt * INV_2LAM_F;            // (l-tau)/(2*lam)
    bool  clamped = (y < NEG_INV_E_F);
    float yc   = fmaxf(y, NEG_INV_E_F);

    // Lambert W init:
    //  y<0: branch series w = -1 + s - s^2/3 + (11/72)s^3, s = sqrt(2(1+e*y))
    //  y>=0: log1p(y)
    float s     = fsqrt(fmaxf(fmaf(2.0f * E_F, yc, 2.0f), 0.0f));
    float w_neg = fmaf(s, fmaf(s, fmaf(s, 11.0f / 72.0f, -1.0f / 3.0f), 1.0f), -1.0f);
    float w_pos = LN2_F * flog2(1.0f + yc);
    float w     = (yc < 0.0f) ? w_neg : w_pos;

    // 2 Halley iterations, single-rcp form
    #pragma unroll
    for (int i = 0; i < 2; ++i) {
        float ew   = fexp2(w * LOG2E_F);
        float f    = fmaf(w, ew, -yc);
        float wp1  = w + 1.0f;
        float num  = 2.0f * f * wp1;
        float den  = fmaf(2.0f * ew, wp1 * wp1, -(w + 2.0f) * f) + 1e-12f;
        w = w - num * frcp(den);
    }

    // loss: unclamped = 0.9*w*(w+2); clamped = lt*e + 0.9
    float loss_un = LAM_F * (w * (w + 2.0f));
    float loss_cl = fmaf(lt, E_F, LAM_F);
    return clamped ? loss_cl : loss_un;
}

__global__ __launch_bounds__(256) void superloss_kernel(
        const float4* __restrict__ p4, const float4* __restrict__ t4,
        float* __restrict__ out, int n4, int n_tail, const float* __restrict__ p_s,
        const float* __restrict__ t_s) {
    int idx    = blockIdx.x * blockDim.x + threadIdx.x;
    int stride = gridDim.x * blockDim.x;
    float acc = 0.0f;
    for (int i = idx; i < n4; i += stride) {
        float4 p = p4[i];
        float4 t = t4[i];
        acc += superloss_elem(p.x, t.x);
        acc += superloss_elem(p.y, t.y);
        acc += superloss_elem(p.z, t.z);
        acc += superloss_elem(p.w, t.w);
    }
    if (idx == 0) {   // tail (n % 4) — n is 2^25 so normally empty
        for (int i = 4 * n4; i < 4 * n4 + n_tail; ++i)
            acc += superloss_elem(p_s[i], t_s[i]);
    }

    // wave64 shuffle reduction
    #pragma unroll
    for (int off = 32; off > 0; off >>= 1)
        acc += __shfl_down(acc, off, 64);

    __shared__ float wsum[4];
    int lane = threadIdx.x & 63;
    int wid  = threadIdx.x >> 6;
    if (lane == 0) wsum[wid] = acc;
    __syncthreads();
    if (threadIdx.x == 0) {
        float sblk = (wsum[0] + wsum[1]) + (wsum[2] + wsum[3]);
        atomicAdd(out, sblk * (1.0f / 32.0f));   // /BATCH_SIZE
    }
}

extern "C" void kernel_launch(void* const* d_in, const int* in_sizes, int n_in,
                              void* d_out, int out_size, void* d_ws, size_t ws_size,
                              hipStream_t stream) {
    const float* logits  = (const float*)d_in[0];
    const float* targets = (const float*)d_in[1];
    float* out = (float*)d_out;
    int n  = in_sizes[0];
    int n4 = n / 4;
    int n_tail = n - 4 * n4;

    // d_out re-poisoned to 0xAA before every timed launch -> zero it
    hipMemsetAsync(d_out, 0, sizeof(float), stream);

    const int block = 256;
    const int grid  = 2048;   // 8192 waves, grid-stride covers 8.39M float4s
    superloss_kernel<<<grid, block, 0, stream>>>(
        (const float4*)logits, (const float4*)targets, out, n4, n_tail,
        logits, targets);
}